// Round 1
// baseline (2610.833 us; speedup 1.0000x reference)
//
#include <hip/hip_runtime.h>

#define C_IN 728
#define NB   16
#define HH   64
#define WW   64
#define HW   4096
#define KPAD 736
#define MPAD 768

typedef __bf16 bf16x8 __attribute__((ext_vector_type(8)));
typedef float  f32x4  __attribute__((ext_vector_type(4)));

// scale = 2^ceil(log2(max(ma,1e-10)/int_max)), exact via frexpf
__device__ __forceinline__ float p2scale(unsigned bits, float int_max) {
    float ma = __uint_as_float(bits);
    float v = fmaxf(ma, 1e-10f) / int_max;
    int e; float m = frexpf(v, &e);     // v = m * 2^e, m in [0.5,1)
    if (m == 0.5f) e -= 1;              // exact power of two: ceil(log2 v)=e-1
    return ldexpf(1.0f, e);
}

__global__ void init_slots(unsigned* slots) {
    if (threadIdx.x < 3) slots[threadIdx.x] = 0u;
}

__device__ __forceinline__ void block_max_atomic(float v, unsigned* slot) {
    #pragma unroll
    for (int off = 32; off; off >>= 1) v = fmaxf(v, __shfl_down(v, off));
    __shared__ float red[4];
    int lane = threadIdx.x & 63, wv = threadIdx.x >> 6;
    if (lane == 0) red[wv] = v;
    __syncthreads();
    if (threadIdx.x == 0) {
        float m = fmaxf(fmaxf(red[0], red[1]), fmaxf(red[2], red[3]));
        atomicMax(slot, __float_as_uint(m));   // all values >= 0: uint order == float order
    }
}

__global__ __launch_bounds__(256) void maxabs_kernel(const float* __restrict__ p, int n,
                                                     unsigned* slot) {
    float v = 0.f;
    for (int i = blockIdx.x * 256 + threadIdx.x; i < n; i += gridDim.x * 256)
        v = fmaxf(v, fabsf(p[i]));
    block_max_atomic(v, slot);
}

// quantize depthwise weights: wq = clip(rint(w/s),-128,127)*s  (f32, exact)
__global__ __launch_bounds__(256) void quant_dw(const float* __restrict__ w,
                                                float* __restrict__ wq,
                                                const unsigned* __restrict__ slots) {
    int i = blockIdx.x * 256 + threadIdx.x;
    if (i >= C_IN * 9) return;
    float s = p2scale(slots[0], 127.f);
    float k = fminf(fmaxf(rintf(w[i] / s), -128.f), 127.f);
    wq[i] = k * s;
}

// depthwise 3x3 (pad 1) + BN(eval) -> y f32 [b][c][h][w]; fused global max|y|
__global__ __launch_bounds__(256) void dwconv_bn(const float* __restrict__ x,
                                                 const float* __restrict__ wq,
                                                 const float* __restrict__ gamma,
                                                 const float* __restrict__ beta,
                                                 const float* __restrict__ rmean,
                                                 const float* __restrict__ rvar,
                                                 float* __restrict__ y,
                                                 unsigned* __restrict__ amax) {
    int idx  = blockIdx.x * 256 + threadIdx.x;          // [0, 16*728*4096)
    int hw   = idx & (HW - 1);
    int rest = idx >> 12;
    int c    = rest % C_IN;
    int b    = rest / C_IN;
    int h = hw >> 6, wc = hw & 63;

    const float* xp = x + (size_t)(b * C_IN + c) * HW;
    const float* wk = wq + c * 9;
    float acc = 0.f;
    #pragma unroll
    for (int dh = -1; dh <= 1; ++dh) {
        int hh = h + dh;
        if ((unsigned)hh < HH) {
            #pragma unroll
            for (int dw = -1; dw <= 1; ++dw) {
                int wwp = wc + dw;
                if ((unsigned)wwp < WW)
                    acc += xp[hh * WW + wwp] * wk[(dh + 1) * 3 + (dw + 1)];
            }
        }
    }
    float inv = gamma[c] / sqrtf(rvar[c] + 1e-5f);
    float val = acc * inv + (beta[c] - rmean[c] * inv);
    y[idx] = val;
    block_max_atomic(fabsf(val), amax);
}

// quantize pointwise weights to INTEGER CODES stored as bf16 bits, padded [768][736]
__global__ __launch_bounds__(256) void quant_wpw(const float* __restrict__ w,
                                                 unsigned short* __restrict__ wq,
                                                 const unsigned* __restrict__ slots) {
    int i = blockIdx.x * 256 + threadIdx.x;
    if (i >= MPAD * KPAD) return;
    int o = i / KPAD, c = i % KPAD;
    float k = 0.f;
    if (o < C_IN && c < C_IN) {
        float s = p2scale(slots[1], 127.f);
        k = fminf(fmaxf(rintf(w[o * C_IN + c] / s), -128.f), 127.f);
    }
    wq[i] = (unsigned short)(__float_as_uint(k) >> 16);  // small ints: bf16-exact truncation
}

// y [b][c][hw] f32 -> quantized integer codes (floor) bf16 at Yq [b][hw][KPAD]
__global__ __launch_bounds__(256) void transpose_quant_y(const float* __restrict__ y,
                                                         unsigned short* __restrict__ yq,
                                                         const unsigned* __restrict__ slots) {
    __shared__ float tile[32][33];
    int tx = threadIdx.x & 31, ty = threadIdx.x >> 5;   // 32 x 8
    int hw0 = blockIdx.x * 32, c0 = blockIdx.y * 32, b = blockIdx.z;
    float inv_s = 1.0f / p2scale(slots[2], 127.f);      // power of two: exact

    #pragma unroll
    for (int i = 0; i < 32; i += 8) {
        int c = c0 + ty + i;
        float v = (c < C_IN) ? y[((size_t)(b * C_IN + c)) * HW + hw0 + tx] : 0.f;
        tile[ty + i][tx] = v;
    }
    __syncthreads();
    #pragma unroll
    for (int i = 0; i < 32; i += 8) {
        int hw = hw0 + ty + i;
        int c  = c0 + tx;
        float k = 0.f;
        if (c < C_IN)
            k = fminf(fmaxf(floorf(tile[tx][ty + i] * inv_s), -128.f), 127.f);
        yq[((size_t)b * HW + hw) * KPAD + c] = (unsigned short)(__float_as_uint(k) >> 16);
    }
}

// GEMM: out[b][o][hw] = s_w*s_y * sum_c Wq[o][c] * Yq[b][hw][c]
// m97 structure: 128x128 tile, 4 waves x (64x64), BK=32, global_load_lds w=16
__global__ __launch_bounds__(256) void gemm_kernel(const unsigned short* __restrict__ Wq,
                                                   const unsigned short* __restrict__ Yq,
                                                   float* __restrict__ out,
                                                   const unsigned* __restrict__ slots) {
    __shared__ __align__(16) unsigned short As[128 * 32];
    __shared__ __align__(16) unsigned short Bs[128 * 32];
    const int t = threadIdx.x;
    const int w = t >> 6, l = t & 63;
    const int r = l & 15, q = l >> 4;
    const int wr = w >> 1, wc = w & 1;
    const int m0 = blockIdx.y * 128;
    const int n0 = blockIdx.x * 128;
    const int b  = blockIdx.z;

    const unsigned short* Ag = Wq + (size_t)m0 * KPAD;
    const unsigned short* Bg = Yq + ((size_t)b * HW + n0) * KPAD;

    const int sm0 = t >> 2;          // staging row, instr 0 (0..63)
    const int sm1 = 64 + sm0;        // staging row, instr 1
    const int sko = (t & 3) * 8;     // k sub-offset (elements)

    f32x4 acc[4][4];
    #pragma unroll
    for (int i = 0; i < 4; ++i)
        #pragma unroll
        for (int j = 0; j < 4; ++j) acc[i][j] = (f32x4){0.f, 0.f, 0.f, 0.f};

    for (int k0 = 0; k0 < KPAD; k0 += 32) {
        __builtin_amdgcn_global_load_lds(
            (const __attribute__((address_space(1))) void*)(Ag + (size_t)sm0 * KPAD + k0 + sko),
            (__attribute__((address_space(3))) void*)(As + w * 512), 16, 0, 0);
        __builtin_amdgcn_global_load_lds(
            (const __attribute__((address_space(1))) void*)(Ag + (size_t)sm1 * KPAD + k0 + sko),
            (__attribute__((address_space(3))) void*)(As + 2048 + w * 512), 16, 0, 0);
        __builtin_amdgcn_global_load_lds(
            (const __attribute__((address_space(1))) void*)(Bg + (size_t)sm0 * KPAD + k0 + sko),
            (__attribute__((address_space(3))) void*)(Bs + w * 512), 16, 0, 0);
        __builtin_amdgcn_global_load_lds(
            (const __attribute__((address_space(1))) void*)(Bg + (size_t)sm1 * KPAD + k0 + sko),
            (__attribute__((address_space(3))) void*)(Bs + 2048 + w * 512), 16, 0, 0);
        __syncthreads();

        bf16x8 af[4], bfr[4];
        #pragma unroll
        for (int fm = 0; fm < 4; ++fm)
            af[fm] = *(const bf16x8*)(As + (wr * 64 + fm * 16 + r) * 32 + q * 8);
        #pragma unroll
        for (int fn = 0; fn < 4; ++fn)
            bfr[fn] = *(const bf16x8*)(Bs + (wc * 64 + fn * 16 + r) * 32 + q * 8);
        #pragma unroll
        for (int fm = 0; fm < 4; ++fm)
            #pragma unroll
            for (int fn = 0; fn < 4; ++fn)
                acc[fm][fn] = __builtin_amdgcn_mfma_f32_16x16x32_bf16(
                    af[fm], bfr[fn], acc[fm][fn], 0, 0, 0);
        __syncthreads();
    }

    const float stot = p2scale(slots[1], 127.f) * p2scale(slots[2], 127.f);
    #pragma unroll
    for (int fm = 0; fm < 4; ++fm) {
        int o = m0 + wr * 64 + fm * 16 + q * 4;
        #pragma unroll
        for (int fn = 0; fn < 4; ++fn) {
            int hw = n0 + wc * 64 + fn * 16 + r;
            float* op = out + ((size_t)b * C_IN + o) * HW + hw;
            #pragma unroll
            for (int reg = 0; reg < 4; ++reg) {
                if (o + reg < C_IN) op[(size_t)reg * HW] = acc[fm][fn][reg] * stot;
            }
        }
    }
}

extern "C" void kernel_launch(void* const* d_in, const int* in_sizes, int n_in,
                              void* d_out, int out_size, void* d_ws, size_t ws_size,
                              hipStream_t stream) {
    const float* x     = (const float*)d_in[0];
    const float* w_dw  = (const float*)d_in[1];
    const float* w_pw  = (const float*)d_in[2];
    const float* gamma = (const float*)d_in[3];
    const float* beta  = (const float*)d_in[4];
    const float* rmean = (const float*)d_in[5];
    const float* rvar  = (const float*)d_in[6];
    float* out = (float*)d_out;

    char* ws = (char*)d_ws;
    unsigned*       slots = (unsigned*)ws;                         // 3 x u32
    float*          wq_dw = (float*)(ws + 256);                    // 6552 f32
    unsigned short* Wq    = (unsigned short*)(ws + 26624);         // [768][736] bf16
    float*          y     = (float*)(ws + 1157120);                // [16][728][4096] f32
    unsigned short* Yq    = (unsigned short*)(ws + 191997952);     // [16][4096][736] bf16
    // total ws use: ~288.5 MB

    init_slots<<<dim3(1), dim3(64), 0, stream>>>(slots);
    maxabs_kernel<<<dim3(26), dim3(256), 0, stream>>>(w_dw, C_IN * 9, slots + 0);
    maxabs_kernel<<<dim3(512), dim3(256), 0, stream>>>(w_pw, C_IN * C_IN, slots + 1);
    quant_dw<<<dim3((C_IN * 9 + 255) / 256), dim3(256), 0, stream>>>(w_dw, wq_dw, slots);
    dwconv_bn<<<dim3(NB * C_IN * HW / 256), dim3(256), 0, stream>>>(
        x, wq_dw, gamma, beta, rmean, rvar, y, slots + 2);
    quant_wpw<<<dim3((MPAD * KPAD + 255) / 256), dim3(256), 0, stream>>>(w_pw, Wq, slots);
    transpose_quant_y<<<dim3(HW / 32, KPAD / 32, NB), dim3(256), 0, stream>>>(y, Yq, slots);
    gemm_kernel<<<dim3(HW / 128, MPAD / 128, NB), dim3(256), 0, stream>>>(Wq, Yq, out, slots);
}

// Round 2
// 606.947 us; speedup vs baseline: 4.3016x; 4.3016x over previous
//
#include <hip/hip_runtime.h>

#define C_IN 728
#define NB   16
#define HH   64
#define WW   64
#define HW   4096
#define KPAD 736
#define MPAD 768

typedef __bf16 bf16x8 __attribute__((ext_vector_type(8)));
typedef float  f32x4  __attribute__((ext_vector_type(4)));

// scale = 2^ceil(log2(max(ma,1e-10)/int_max)), exact via frexpf
__device__ __forceinline__ float p2scale(unsigned bits, float int_max) {
    float ma = __uint_as_float(bits);
    float v = fmaxf(ma, 1e-10f) / int_max;
    int e; float m = frexpf(v, &e);     // v = m * 2^e, m in [0.5,1)
    if (m == 0.5f) e -= 1;              // exact power of two: ceil(log2 v)=e-1
    return ldexpf(1.0f, e);
}

__global__ void init_slots(unsigned* slots) {
    if (threadIdx.x < 3) slots[threadIdx.x] = 0u;
}

__device__ __forceinline__ float block_max(float v) {
    #pragma unroll
    for (int off = 32; off; off >>= 1) v = fmaxf(v, __shfl_down(v, off));
    __shared__ float red[4];
    int lane = threadIdx.x & 63, wv = threadIdx.x >> 6;
    if (lane == 0) red[wv] = v;
    __syncthreads();
    return fmaxf(fmaxf(red[0], red[1]), fmaxf(red[2], red[3]));
}

__global__ __launch_bounds__(256) void maxabs_kernel(const float* __restrict__ p, int n,
                                                     unsigned* slot) {
    float v = 0.f;
    for (int i = blockIdx.x * 256 + threadIdx.x; i < n; i += gridDim.x * 256)
        v = fmaxf(v, fabsf(p[i]));
    float m = block_max(v);
    if (threadIdx.x == 0)
        atomicMax(slot, __float_as_uint(m));   // few blocks: negligible contention
}

// quantize depthwise weights: wq = clip(rint(w/s),-128,127)*s  (f32, exact)
__global__ __launch_bounds__(256) void quant_dw(const float* __restrict__ w,
                                                float* __restrict__ wq,
                                                const unsigned* __restrict__ slots) {
    int i = blockIdx.x * 256 + threadIdx.x;
    if (i >= C_IN * 9) return;
    float s = p2scale(slots[0], 127.f);
    float k = fminf(fmaxf(rintf(w[i] / s), -128.f), 127.f);
    wq[i] = k * s;
}

// depthwise 3x3 (pad 1) + BN(eval) -> y f32 [b][c][h][w]; per-block max -> partial[]
// one block per (b,c) plane; plane staged in LDS
__global__ __launch_bounds__(256) void dwconv_bn(const float* __restrict__ x,
                                                 const float* __restrict__ wq,
                                                 const float* __restrict__ gamma,
                                                 const float* __restrict__ beta,
                                                 const float* __restrict__ rmean,
                                                 const float* __restrict__ rvar,
                                                 float* __restrict__ y,
                                                 float* __restrict__ partial) {
    __shared__ __align__(16) float tile[HW];
    const int c = blockIdx.x, b = blockIdx.y, t = threadIdx.x;
    const float* xp = x + ((size_t)b * C_IN + c) * HW;

    const float4* xv = (const float4*)xp;
    float4* tv = (float4*)tile;
    #pragma unroll
    for (int i = 0; i < 4; ++i) tv[t + i * 256] = xv[t + i * 256];

    float wk[9];
    #pragma unroll
    for (int j = 0; j < 9; ++j) wk[j] = wq[c * 9 + j];
    const float inv  = gamma[c] / sqrtf(rvar[c] + 1e-5f);
    const float bias = beta[c] - rmean[c] * inv;
    __syncthreads();

    float* yp = y + ((size_t)b * C_IN + c) * HW;
    float vmax = 0.f;
    #pragma unroll
    for (int i = 0; i < 16; ++i) {
        const int p = t + i * 256;
        const int h = p >> 6, wc = p & 63;
        float acc = 0.f;
        #pragma unroll
        for (int dh = -1; dh <= 1; ++dh) {
            const int hh = h + dh;
            if ((unsigned)hh < (unsigned)HH) {
                const int base = hh << 6;
                if (wc > 0)  acc += tile[base + wc - 1] * wk[(dh + 1) * 3 + 0];
                acc += tile[base + wc] * wk[(dh + 1) * 3 + 1];
                if (wc < 63) acc += tile[base + wc + 1] * wk[(dh + 1) * 3 + 2];
            }
        }
        const float val = acc * inv + bias;
        yp[p] = val;
        vmax = fmaxf(vmax, fabsf(val));
    }
    const float m = block_max(vmax);
    if (t == 0) partial[b * C_IN + c] = m;   // plain store, no atomic
}

// single-block reduce of partial[] -> slot (bits of nonneg float)
__global__ __launch_bounds__(256) void reduce_partial(const float* __restrict__ p, int n,
                                                      unsigned* __restrict__ slot) {
    float v = 0.f;
    for (int i = threadIdx.x; i < n; i += 256) v = fmaxf(v, p[i]);
    float m = block_max(v);
    if (threadIdx.x == 0) *slot = __float_as_uint(m);
}

// quantize pointwise weights to INTEGER CODES stored as bf16 bits, padded [768][736]
__global__ __launch_bounds__(256) void quant_wpw(const float* __restrict__ w,
                                                 unsigned short* __restrict__ wq,
                                                 const unsigned* __restrict__ slots) {
    int i = blockIdx.x * 256 + threadIdx.x;
    if (i >= MPAD * KPAD) return;
    int o = i / KPAD, c = i % KPAD;
    float k = 0.f;
    if (o < C_IN && c < C_IN) {
        float s = p2scale(slots[1], 127.f);
        k = fminf(fmaxf(rintf(w[o * C_IN + c] / s), -128.f), 127.f);
    }
    wq[i] = (unsigned short)(__float_as_uint(k) >> 16);  // small ints: bf16-exact truncation
}

// y [b][c][hw] f32 -> quantized integer codes (floor) bf16 at Yq [b][hw][KPAD]
__global__ __launch_bounds__(256) void transpose_quant_y(const float* __restrict__ y,
                                                         unsigned short* __restrict__ yq,
                                                         const unsigned* __restrict__ slots) {
    __shared__ float tile[32][33];
    int tx = threadIdx.x & 31, ty = threadIdx.x >> 5;   // 32 x 8
    int hw0 = blockIdx.x * 32, c0 = blockIdx.y * 32, b = blockIdx.z;
    float inv_s = 1.0f / p2scale(slots[2], 127.f);      // power of two: exact

    #pragma unroll
    for (int i = 0; i < 32; i += 8) {
        int c = c0 + ty + i;
        float v = (c < C_IN) ? y[((size_t)(b * C_IN + c)) * HW + hw0 + tx] : 0.f;
        tile[ty + i][tx] = v;
    }
    __syncthreads();
    #pragma unroll
    for (int i = 0; i < 32; i += 8) {
        int hw = hw0 + ty + i;
        int c  = c0 + tx;
        float k = 0.f;
        if (c < C_IN)
            k = fminf(fmaxf(floorf(tile[tx][ty + i] * inv_s), -128.f), 127.f);
        yq[((size_t)b * HW + hw) * KPAD + c] = (unsigned short)(__float_as_uint(k) >> 16);
    }
}

// GEMM: out[b][o][hw] = s_w*s_y * sum_c Wq[o][c] * Yq[b][hw][c]
// m97 structure: 128x128 tile, 4 waves x (64x64), BK=32, global_load_lds w=16
__global__ __launch_bounds__(256) void gemm_kernel(const unsigned short* __restrict__ Wq,
                                                   const unsigned short* __restrict__ Yq,
                                                   float* __restrict__ out,
                                                   const unsigned* __restrict__ slots) {
    __shared__ __align__(16) unsigned short As[128 * 32];
    __shared__ __align__(16) unsigned short Bs[128 * 32];
    const int t = threadIdx.x;
    const int w = t >> 6, l = t & 63;
    const int r = l & 15, q = l >> 4;
    const int wr = w >> 1, wc = w & 1;
    const int m0 = blockIdx.y * 128;
    const int n0 = blockIdx.x * 128;
    const int b  = blockIdx.z;

    const unsigned short* Ag = Wq + (size_t)m0 * KPAD;
    const unsigned short* Bg = Yq + ((size_t)b * HW + n0) * KPAD;

    const int sm0 = t >> 2;          // staging row, instr 0 (0..63)
    const int sm1 = 64 + sm0;        // staging row, instr 1
    const int sko = (t & 3) * 8;     // k sub-offset (elements)

    f32x4 acc[4][4];
    #pragma unroll
    for (int i = 0; i < 4; ++i)
        #pragma unroll
        for (int j = 0; j < 4; ++j) acc[i][j] = (f32x4){0.f, 0.f, 0.f, 0.f};

    for (int k0 = 0; k0 < KPAD; k0 += 32) {
        __builtin_amdgcn_global_load_lds(
            (const __attribute__((address_space(1))) void*)(Ag + (size_t)sm0 * KPAD + k0 + sko),
            (__attribute__((address_space(3))) void*)(As + w * 512), 16, 0, 0);
        __builtin_amdgcn_global_load_lds(
            (const __attribute__((address_space(1))) void*)(Ag + (size_t)sm1 * KPAD + k0 + sko),
            (__attribute__((address_space(3))) void*)(As + 2048 + w * 512), 16, 0, 0);
        __builtin_amdgcn_global_load_lds(
            (const __attribute__((address_space(1))) void*)(Bg + (size_t)sm0 * KPAD + k0 + sko),
            (__attribute__((address_space(3))) void*)(Bs + w * 512), 16, 0, 0);
        __builtin_amdgcn_global_load_lds(
            (const __attribute__((address_space(1))) void*)(Bg + (size_t)sm1 * KPAD + k0 + sko),
            (__attribute__((address_space(3))) void*)(Bs + 2048 + w * 512), 16, 0, 0);
        __syncthreads();

        bf16x8 af[4], bfr[4];
        #pragma unroll
        for (int fm = 0; fm < 4; ++fm)
            af[fm] = *(const bf16x8*)(As + (wr * 64 + fm * 16 + r) * 32 + q * 8);
        #pragma unroll
        for (int fn = 0; fn < 4; ++fn)
            bfr[fn] = *(const bf16x8*)(Bs + (wc * 64 + fn * 16 + r) * 32 + q * 8);
        #pragma unroll
        for (int fm = 0; fm < 4; ++fm)
            #pragma unroll
            for (int fn = 0; fn < 4; ++fn)
                acc[fm][fn] = __builtin_amdgcn_mfma_f32_16x16x32_bf16(
                    af[fm], bfr[fn], acc[fm][fn], 0, 0, 0);
        __syncthreads();
    }

    const float stot = p2scale(slots[1], 127.f) * p2scale(slots[2], 127.f);
    #pragma unroll
    for (int fm = 0; fm < 4; ++fm) {
        int o = m0 + wr * 64 + fm * 16 + q * 4;
        #pragma unroll
        for (int fn = 0; fn < 4; ++fn) {
            int hw = n0 + wc * 64 + fn * 16 + r;
            float* op = out + ((size_t)b * C_IN + o) * HW + hw;
            #pragma unroll
            for (int reg = 0; reg < 4; ++reg) {
                if (o + reg < C_IN) op[(size_t)reg * HW] = acc[fm][fn][reg] * stot;
            }
        }
    }
}

extern "C" void kernel_launch(void* const* d_in, const int* in_sizes, int n_in,
                              void* d_out, int out_size, void* d_ws, size_t ws_size,
                              hipStream_t stream) {
    const float* x     = (const float*)d_in[0];
    const float* w_dw  = (const float*)d_in[1];
    const float* w_pw  = (const float*)d_in[2];
    const float* gamma = (const float*)d_in[3];
    const float* beta  = (const float*)d_in[4];
    const float* rmean = (const float*)d_in[5];
    const float* rvar  = (const float*)d_in[6];
    float* out = (float*)d_out;

    char* ws = (char*)d_ws;
    unsigned*       slots = (unsigned*)ws;                         // 3 x u32
    float*          wq_dw = (float*)(ws + 256);                    // 6552 f32
    unsigned short* Wq    = (unsigned short*)(ws + 26624);         // [768][736] bf16
    float*          y     = (float*)(ws + 1157120);                // [16][728][4096] f32
    unsigned short* Yq    = (unsigned short*)(ws + 191997952);     // [16][4096][736] bf16
    // partial[] aliases the Yq region: consumed by reduce_partial BEFORE
    // transpose_quant_y writes Yq (stream-ordered, safe)
    float*          partial = (float*)(ws + 191997952);            // 11648 f32

    init_slots<<<dim3(1), dim3(64), 0, stream>>>(slots);
    maxabs_kernel<<<dim3(4), dim3(256), 0, stream>>>(w_dw, C_IN * 9, slots + 0);
    maxabs_kernel<<<dim3(64), dim3(256), 0, stream>>>(w_pw, C_IN * C_IN, slots + 1);
    quant_dw<<<dim3((C_IN * 9 + 255) / 256), dim3(256), 0, stream>>>(w_dw, wq_dw, slots);
    dwconv_bn<<<dim3(C_IN, NB), dim3(256), 0, stream>>>(
        x, wq_dw, gamma, beta, rmean, rvar, y, partial);
    reduce_partial<<<dim3(1), dim3(256), 0, stream>>>(partial, NB * C_IN, slots + 2);
    quant_wpw<<<dim3((MPAD * KPAD + 255) / 256), dim3(256), 0, stream>>>(w_pw, Wq, slots);
    transpose_quant_y<<<dim3(HW / 32, KPAD / 32, NB), dim3(256), 0, stream>>>(y, Yq, slots);
    gemm_kernel<<<dim3(HW / 128, MPAD / 128, NB), dim3(256), 0, stream>>>(Wq, Yq, out, slots);
}

// Round 6
// 581.575 us; speedup vs baseline: 4.4892x; 1.0436x over previous
//
#include <hip/hip_runtime.h>

#define C_IN 728
#define NB   16
#define HH   64
#define WW   64
#define HW   4096
#define KPAD 736
#define MPAD 768

typedef __bf16 bf16x8 __attribute__((ext_vector_type(8)));
typedef float  f32x4  __attribute__((ext_vector_type(4)));
typedef unsigned short us8 __attribute__((ext_vector_type(8)));

// scale = 2^ceil(log2(max(ma,1e-10)/int_max)), exact via frexpf
__device__ __forceinline__ float p2scale(unsigned bits, float int_max) {
    float ma = __uint_as_float(bits);
    float v = fmaxf(ma, 1e-10f) / int_max;
    int e; float m = frexpf(v, &e);     // v = m * 2^e, m in [0.5,1)
    if (m == 0.5f) e -= 1;              // exact power of two: ceil(log2 v)=e-1
    return ldexpf(1.0f, e);
}

__global__ void init_slots(unsigned* slots) {
    if (threadIdx.x < 3) slots[threadIdx.x] = 0u;
}

__device__ __forceinline__ float block_max(float v) {
    #pragma unroll
    for (int off = 32; off; off >>= 1) v = fmaxf(v, __shfl_down(v, off));
    __shared__ float red[4];
    int lane = threadIdx.x & 63, wv = threadIdx.x >> 6;
    if (lane == 0) red[wv] = v;
    __syncthreads();
    return fmaxf(fmaxf(red[0], red[1]), fmaxf(red[2], red[3]));
}

__global__ __launch_bounds__(256) void maxabs_kernel(const float* __restrict__ p, int n,
                                                     unsigned* slot) {
    float v = 0.f;
    for (int i = blockIdx.x * 256 + threadIdx.x; i < n; i += gridDim.x * 256)
        v = fmaxf(v, fabsf(p[i]));
    float m = block_max(v);
    if (threadIdx.x == 0)
        atomicMax(slot, __float_as_uint(m));   // few blocks: negligible contention
}

// quantize depthwise weights: wq = clip(rint(w/s),-128,127)*s  (f32, exact)
__global__ __launch_bounds__(256) void quant_dw(const float* __restrict__ w,
                                                float* __restrict__ wq,
                                                const unsigned* __restrict__ slots) {
    int i = blockIdx.x * 256 + threadIdx.x;
    if (i >= C_IN * 9) return;
    float s = p2scale(slots[0], 127.f);
    float k = fminf(fmaxf(rintf(w[i] / s), -128.f), 127.f);
    wq[i] = k * s;
}

// depthwise 3x3 (pad 1) + BN(eval) -> y f32 [b][c][h][w]; per-block max -> partial[]
__global__ __launch_bounds__(256) void dwconv_bn(const float* __restrict__ x,
                                                 const float* __restrict__ wq,
                                                 const float* __restrict__ gamma,
                                                 const float* __restrict__ beta,
                                                 const float* __restrict__ rmean,
                                                 const float* __restrict__ rvar,
                                                 float* __restrict__ y,
                                                 float* __restrict__ partial) {
    __shared__ __align__(16) float tile[HW];
    const int c = blockIdx.x, b = blockIdx.y, t = threadIdx.x;
    const float* xp = x + ((size_t)b * C_IN + c) * HW;

    const float4* xv = (const float4*)xp;
    float4* tv = (float4*)tile;
    #pragma unroll
    for (int i = 0; i < 4; ++i) tv[t + i * 256] = xv[t + i * 256];

    float wk[9];
    #pragma unroll
    for (int j = 0; j < 9; ++j) wk[j] = wq[c * 9 + j];
    const float inv  = gamma[c] / sqrtf(rvar[c] + 1e-5f);
    const float bias = beta[c] - rmean[c] * inv;
    __syncthreads();

    float* yp = y + ((size_t)b * C_IN + c) * HW;
    float vmax = 0.f;
    #pragma unroll
    for (int i = 0; i < 16; ++i) {
        const int p = t + i * 256;
        const int h = p >> 6, wc = p & 63;
        float acc = 0.f;
        #pragma unroll
        for (int dh = -1; dh <= 1; ++dh) {
            const int hh = h + dh;
            if ((unsigned)hh < (unsigned)HH) {
                const int base = hh << 6;
                if (wc > 0)  acc += tile[base + wc - 1] * wk[(dh + 1) * 3 + 0];
                acc += tile[base + wc] * wk[(dh + 1) * 3 + 1];
                if (wc < 63) acc += tile[base + wc + 1] * wk[(dh + 1) * 3 + 2];
            }
        }
        const float val = acc * inv + bias;
        yp[p] = val;
        vmax = fmaxf(vmax, fabsf(val));
    }
    const float m = block_max(vmax);
    if (t == 0) partial[b * C_IN + c] = m;   // plain store, no atomic
}

// single-block reduce of partial[] -> slot (bits of nonneg float)
__global__ __launch_bounds__(256) void reduce_partial(const float* __restrict__ p, int n,
                                                      unsigned* __restrict__ slot) {
    float v = 0.f;
    for (int i = threadIdx.x; i < n; i += 256) v = fmaxf(v, p[i]);
    float m = block_max(v);
    if (threadIdx.x == 0) *slot = __float_as_uint(m);
}

// quantize pointwise weights to INTEGER CODES stored as bf16 bits, padded [768][736]
__global__ __launch_bounds__(256) void quant_wpw(const float* __restrict__ w,
                                                 unsigned short* __restrict__ wq,
                                                 const unsigned* __restrict__ slots) {
    int i = blockIdx.x * 256 + threadIdx.x;
    if (i >= MPAD * KPAD) return;
    int o = i / KPAD, c = i % KPAD;
    float k = 0.f;
    if (o < C_IN && c < C_IN) {
        float s = p2scale(slots[1], 127.f);
        k = fminf(fmaxf(rintf(w[o * C_IN + c] / s), -128.f), 127.f);
    }
    wq[i] = (unsigned short)(__float_as_uint(k) >> 16);  // small ints: bf16-exact truncation
}

// y [b][c][hw] f32 -> quantized integer codes (floor) bf16 at Yq [b][hw][KPAD]
// 128c x 32hw tile; float4 loads, granule-swizzled LDS [128][36], ushort8 stores
__global__ __launch_bounds__(256) void transpose_quant_y(const float* __restrict__ y,
                                                         unsigned short* __restrict__ yq,
                                                         const unsigned* __restrict__ slots) {
    __shared__ __align__(16) float tile[128 * 36];
    const int t   = threadIdx.x;
    const int hw0 = blockIdx.x * 32;
    const int c0  = blockIdx.y * 128;
    const int b   = blockIdx.z;
    const float inv_s = 1.0f / p2scale(slots[2], 127.f);   // power of two: exact

    // load phase: 128 c-rows x 32 hw, 8 granules (float4) per row
    #pragma unroll
    for (int i = 0; i < 4; ++i) {
        const int gi = i * 256 + t;
        const int cl = gi >> 3, g = gi & 7;
        const int c  = c0 + cl;
        float4 v = make_float4(0.f, 0.f, 0.f, 0.f);
        if (c < C_IN)
            v = *(const float4*)(y + ((size_t)(b * C_IN + c)) * HW + hw0 + g * 4);
        const int gp = g ^ ((cl >> 3) & 7);                // bank swizzle
        *(float4*)(tile + cl * 36 + gp * 4) = v;
    }
    __syncthreads();

    // write phase: each thread emits 8 bf16 codes (16 B) for one hw row
    #pragma unroll
    for (int it = 0; it < 2; ++it) {
        const int hw_r = (t >> 4) + it * 16;
        const int c8   = t & 15;
        const int c_out = c0 + c8 * 8;
        if (c_out < KPAD) {
            us8 pack;
            #pragma unroll
            for (int j = 0; j < 8; ++j) {
                const int cl = c8 * 8 + j;
                const int gp = (hw_r >> 2) ^ (c8 & 7);
                const float v = tile[cl * 36 + gp * 4 + (hw_r & 3)];
                const float k = fminf(fmaxf(floorf(v * inv_s), -128.f), 127.f);
                pack[j] = (unsigned short)(__float_as_uint(k) >> 16);
            }
            *(us8*)(yq + ((size_t)b * HW + hw0 + hw_r) * KPAD + c_out) = pack;
        }
    }
}

// GEMM: out[b][o][hw] = s_w*s_y * sum_c Wq[o][c] * Yq[b][hw][c]
// m97 structure + XOR granule swizzle (pre-swizzled global source, rule 21)
__global__ __launch_bounds__(256) void gemm_kernel(const unsigned short* __restrict__ Wq,
                                                   const unsigned short* __restrict__ Yq,
                                                   float* __restrict__ out,
                                                   const unsigned* __restrict__ slots) {
    __shared__ __align__(16) unsigned short As[128 * 32];
    __shared__ __align__(16) unsigned short Bs[128 * 32];
    const int t = threadIdx.x;
    const int w = t >> 6, l = t & 63;
    const int r = l & 15, q = l >> 4;
    const int wr = w >> 1, wc = w & 1;
    const int m0 = blockIdx.y * 128;
    const int n0 = blockIdx.x * 128;
    const int b  = blockIdx.z;

    const unsigned short* Ag = Wq + (size_t)m0 * KPAD;
    const unsigned short* Bg = Yq + ((size_t)b * HW + n0) * KPAD;

    const int srow = t >> 2;                       // staging row (0..63)
    // source granule pre-swizzle: slot s=(t&3) holds granule s ^ ((row>>1)&3)
    const int sko  = ((t & 3) ^ ((t >> 3) & 3)) * 8;
    const int swr  = (r >> 1) & 3;                 // read-side swizzle

    f32x4 acc[4][4];
    #pragma unroll
    for (int i = 0; i < 4; ++i)
        #pragma unroll
        for (int j = 0; j < 4; ++j) acc[i][j] = (f32x4){0.f, 0.f, 0.f, 0.f};

    for (int k0 = 0; k0 < KPAD; k0 += 32) {
        __builtin_amdgcn_global_load_lds(
            (const __attribute__((address_space(1))) void*)(Ag + (size_t)srow * KPAD + k0 + sko),
            (__attribute__((address_space(3))) void*)(As + w * 512), 16, 0, 0);
        __builtin_amdgcn_global_load_lds(
            (const __attribute__((address_space(1))) void*)(Ag + (size_t)(64 + srow) * KPAD + k0 + sko),
            (__attribute__((address_space(3))) void*)(As + 2048 + w * 512), 16, 0, 0);
        __builtin_amdgcn_global_load_lds(
            (const __attribute__((address_space(1))) void*)(Bg + (size_t)srow * KPAD + k0 + sko),
            (__attribute__((address_space(3))) void*)(Bs + w * 512), 16, 0, 0);
        __builtin_amdgcn_global_load_lds(
            (const __attribute__((address_space(1))) void*)(Bg + (size_t)(64 + srow) * KPAD + k0 + sko),
            (__attribute__((address_space(3))) void*)(Bs + 2048 + w * 512), 16, 0, 0);
        __syncthreads();

        bf16x8 af[4], bfr[4];
        #pragma unroll
        for (int fm = 0; fm < 4; ++fm)
            af[fm] = *(const bf16x8*)(As + (wr * 64 + fm * 16 + r) * 32 + ((q ^ swr)) * 8);
        #pragma unroll
        for (int fn = 0; fn < 4; ++fn)
            bfr[fn] = *(const bf16x8*)(Bs + (wc * 64 + fn * 16 + r) * 32 + ((q ^ swr)) * 8);
        #pragma unroll
        for (int fm = 0; fm < 4; ++fm)
            #pragma unroll
            for (int fn = 0; fn < 4; ++fn)
                acc[fm][fn] = __builtin_amdgcn_mfma_f32_16x16x32_bf16(
                    af[fm], bfr[fn], acc[fm][fn], 0, 0, 0);
        __syncthreads();
    }

    const float stot = p2scale(slots[1], 127.f) * p2scale(slots[2], 127.f);
    #pragma unroll
    for (int fm = 0; fm < 4; ++fm) {
        int o = m0 + wr * 64 + fm * 16 + q * 4;
        #pragma unroll
        for (int fn = 0; fn < 4; ++fn) {
            int hw = n0 + wc * 64 + fn * 16 + r;
            float* op = out + ((size_t)b * C_IN + o) * HW + hw;
            #pragma unroll
            for (int reg = 0; reg < 4; ++reg) {
                if (o + reg < C_IN) op[(size_t)reg * HW] = acc[fm][fn][reg] * stot;
            }
        }
    }
}

extern "C" void kernel_launch(void* const* d_in, const int* in_sizes, int n_in,
                              void* d_out, int out_size, void* d_ws, size_t ws_size,
                              hipStream_t stream) {
    const float* x     = (const float*)d_in[0];
    const float* w_dw  = (const float*)d_in[1];
    const float* w_pw  = (const float*)d_in[2];
    const float* gamma = (const float*)d_in[3];
    const float* beta  = (const float*)d_in[4];
    const float* rmean = (const float*)d_in[5];
    const float* rvar  = (const float*)d_in[6];
    float* out = (float*)d_out;

    char* ws = (char*)d_ws;
    unsigned*       slots = (unsigned*)ws;                         // 3 x u32
    float*          wq_dw = (float*)(ws + 256);                    // 6552 f32
    unsigned short* Wq    = (unsigned short*)(ws + 26624);         // [768][736] bf16
    float*          y     = (float*)(ws + 1157120);                // [16][728][4096] f32
    unsigned short* Yq    = (unsigned short*)(ws + 191997952);     // [16][4096][736] bf16
    // partial[] aliases the Yq region: consumed by reduce_partial BEFORE
    // transpose_quant_y writes Yq (stream-ordered, safe)
    float*          partial = (float*)(ws + 191997952);            // 11648 f32

    init_slots<<<dim3(1), dim3(64), 0, stream>>>(slots);
    maxabs_kernel<<<dim3(4), dim3(256), 0, stream>>>(w_dw, C_IN * 9, slots + 0);
    maxabs_kernel<<<dim3(64), dim3(256), 0, stream>>>(w_pw, C_IN * C_IN, slots + 1);
    quant_dw<<<dim3((C_IN * 9 + 255) / 256), dim3(256), 0, stream>>>(w_dw, wq_dw, slots);
    dwconv_bn<<<dim3(C_IN, NB), dim3(256), 0, stream>>>(
        x, wq_dw, gamma, beta, rmean, rvar, y, partial);
    reduce_partial<<<dim3(1), dim3(256), 0, stream>>>(partial, NB * C_IN, slots + 2);
    quant_wpw<<<dim3((MPAD * KPAD + 255) / 256), dim3(256), 0, stream>>>(w_pw, Wq, slots);
    transpose_quant_y<<<dim3(HW / 32, KPAD / 128 + 1, NB), dim3(256), 0, stream>>>(y, Yq, slots);
    gemm_kernel<<<dim3(HW / 128, MPAD / 128, NB), dim3(256), 0, stream>>>(Wq, Yq, out, slots);
}

// Round 8
// 575.094 us; speedup vs baseline: 4.5398x; 1.0113x over previous
//
#include <hip/hip_runtime.h>

#define C_IN 728
#define NB   16
#define HH   64
#define WW   64
#define HW   4096
#define KPAD 736
#define MPAD 768
#define PROW 68   // padded LDS row stride (floats): 66 used + 2 pad = 272 B (17 granules)

typedef __bf16 bf16x8 __attribute__((ext_vector_type(8)));
typedef float  f32x4  __attribute__((ext_vector_type(4)));
typedef unsigned short us8 __attribute__((ext_vector_type(8)));

// scale = 2^ceil(log2(max(ma,1e-10)/int_max)), exact via frexpf
__device__ __forceinline__ float p2scale(unsigned bits, float int_max) {
    float ma = __uint_as_float(bits);
    float v = fmaxf(ma, 1e-10f) / int_max;
    int e; float m = frexpf(v, &e);     // v = m * 2^e, m in [0.5,1)
    if (m == 0.5f) e -= 1;              // exact power of two: ceil(log2 v)=e-1
    return ldexpf(1.0f, e);
}

__global__ void init_slots(unsigned* slots) {
    if (threadIdx.x < 3) slots[threadIdx.x] = 0u;
}

__device__ __forceinline__ float block_max(float v) {
    #pragma unroll
    for (int off = 32; off; off >>= 1) v = fmaxf(v, __shfl_down(v, off));
    __shared__ float red[4];
    int lane = threadIdx.x & 63, wv = threadIdx.x >> 6;
    if (lane == 0) red[wv] = v;
    __syncthreads();
    return fmaxf(fmaxf(red[0], red[1]), fmaxf(red[2], red[3]));
}

__global__ __launch_bounds__(256) void maxabs_kernel(const float* __restrict__ p, int n,
                                                     unsigned* slot) {
    float v = 0.f;
    for (int i = blockIdx.x * 256 + threadIdx.x; i < n; i += gridDim.x * 256)
        v = fmaxf(v, fabsf(p[i]));
    float m = block_max(v);
    if (threadIdx.x == 0)
        atomicMax(slot, __float_as_uint(m));   // few blocks: negligible contention
}

// quantize depthwise weights: wq = clip(rint(w/s),-128,127)*s  (f32, exact)
__global__ __launch_bounds__(256) void quant_dw(const float* __restrict__ w,
                                                float* __restrict__ wq,
                                                const unsigned* __restrict__ slots) {
    int i = blockIdx.x * 256 + threadIdx.x;
    if (i >= C_IN * 9) return;
    float s = p2scale(slots[0], 127.f);
    float k = fminf(fmaxf(rintf(w[i] / s), -128.f), 127.f);
    wq[i] = k * s;
}

// depthwise 3x3 (pad 1) + BN(eval) -> y f32 [b][c][h][w]; per-block max -> partial[]
// zero-halo LDS plane [66][PROW]; thread = one 16-px row strip; 15x ds_read_b128
__global__ __launch_bounds__(256) void dwconv_bn(const float* __restrict__ x,
                                                 const float* __restrict__ wq,
                                                 const float* __restrict__ gamma,
                                                 const float* __restrict__ beta,
                                                 const float* __restrict__ rmean,
                                                 const float* __restrict__ rvar,
                                                 float* __restrict__ y,
                                                 float* __restrict__ partial) {
    __shared__ __align__(16) float tile[66 * PROW];
    const int c = blockIdx.x, b = blockIdx.y, t = threadIdx.x;
    const float* xp = x + ((size_t)b * C_IN + c) * HW;

    // zero halo: full rows 0 and 65; cols {0,65,66,67} of rows 1..64
    if (t < 136) { int hr = t / PROW, cc = t - hr * PROW; tile[hr * 65 * PROW + cc] = 0.f; }
    { int hr = 1 + (t & 63); int g = t >> 6; int cc = (g == 0) ? 0 : (64 + g);
      tile[hr * PROW + cc] = 0.f; }

    // stage interior: coalesced float4 global loads, scalar LDS writes (dest col +1)
    const float4* xv = (const float4*)xp;
    #pragma unroll
    for (int i = 0; i < 4; ++i) {
        const int idx4 = t + i * 256;
        const float4 v = xv[idx4];
        const int h = idx4 >> 4, c4 = idx4 & 15;
        float* dst = tile + (h + 1) * PROW + 4 * c4 + 1;
        dst[0] = v.x; dst[1] = v.y; dst[2] = v.z; dst[3] = v.w;
    }

    float wk[9];
    #pragma unroll
    for (int j = 0; j < 9; ++j) wk[j] = wq[c * 9 + j];
    const float inv  = gamma[c] / sqrtf(rvar[c] + 1e-5f);
    const float bias = beta[c] - rmean[c] * inv;
    __syncthreads();

    // compute: thread -> row r = t>>2, cols 16*qt .. 16*qt+15
    const int r = t >> 2, qt = t & 3;
    float acc[16];
    #pragma unroll
    for (int j = 0; j < 16; ++j) acc[j] = 0.f;

    #pragma unroll
    for (int dr = 0; dr < 3; ++dr) {
        // padded row r+dr, float base = 16*qt (covers padded cols 16qt..16qt+19)
        const float* rowp = tile + (r + dr) * PROW + 16 * qt;   // 16B-aligned
        float rv[20];
        #pragma unroll
        for (int i = 0; i < 5; ++i)
            *(f32x4*)(rv + 4 * i) = *(const f32x4*)(rowp + 4 * i);
        const float w0 = wk[dr * 3 + 0], w1 = wk[dr * 3 + 1], w2 = wk[dr * 3 + 2];
        #pragma unroll
        for (int j = 0; j < 16; ++j)
            acc[j] += rv[j] * w0 + rv[j + 1] * w1 + rv[j + 2] * w2;
    }

    float* yp = y + ((size_t)b * C_IN + c) * HW + r * WW + 16 * qt;
    float vmax = 0.f;
    #pragma unroll
    for (int j4 = 0; j4 < 4; ++j4) {
        float4 o;
        o.x = acc[4 * j4 + 0] * inv + bias;
        o.y = acc[4 * j4 + 1] * inv + bias;
        o.z = acc[4 * j4 + 2] * inv + bias;
        o.w = acc[4 * j4 + 3] * inv + bias;
        vmax = fmaxf(vmax, fmaxf(fmaxf(fabsf(o.x), fabsf(o.y)),
                                 fmaxf(fabsf(o.z), fabsf(o.w))));
        ((float4*)yp)[j4] = o;
    }
    const float m = block_max(vmax);
    if (t == 0) partial[b * C_IN + c] = m;   // plain store, no atomic
}

// single-block reduce of partial[] -> slot (bits of nonneg float)
__global__ __launch_bounds__(256) void reduce_partial(const float* __restrict__ p, int n,
                                                      unsigned* __restrict__ slot) {
    float v = 0.f;
    for (int i = threadIdx.x; i < n; i += 256) v = fmaxf(v, p[i]);
    float m = block_max(v);
    if (threadIdx.x == 0) *slot = __float_as_uint(m);
}

// quantize pointwise weights to INTEGER CODES stored as bf16 bits, padded [768][736]
__global__ __launch_bounds__(256) void quant_wpw(const float* __restrict__ w,
                                                 unsigned short* __restrict__ wq,
                                                 const unsigned* __restrict__ slots) {
    int i = blockIdx.x * 256 + threadIdx.x;
    if (i >= MPAD * KPAD) return;
    int o = i / KPAD, c = i % KPAD;
    float k = 0.f;
    if (o < C_IN && c < C_IN) {
        float s = p2scale(slots[1], 127.f);
        k = fminf(fmaxf(rintf(w[o * C_IN + c] / s), -128.f), 127.f);
    }
    wq[i] = (unsigned short)(__float_as_uint(k) >> 16);  // small ints: bf16-exact truncation
}

// y [b][c][hw] f32 -> quantized integer codes (floor) bf16 at Yq [b][hw][KPAD]
// 128c x 32hw tile; float4 loads, granule-swizzled LDS [128][36], ushort8 stores
__global__ __launch_bounds__(256) void transpose_quant_y(const float* __restrict__ y,
                                                         unsigned short* __restrict__ yq,
                                                         const unsigned* __restrict__ slots) {
    __shared__ __align__(16) float tile[128 * 36];
    const int t   = threadIdx.x;
    const int hw0 = blockIdx.x * 32;
    const int c0  = blockIdx.y * 128;
    const int b   = blockIdx.z;
    const float inv_s = 1.0f / p2scale(slots[2], 127.f);   // power of two: exact

    // load phase: 128 c-rows x 32 hw, 8 granules (float4) per row
    #pragma unroll
    for (int i = 0; i < 4; ++i) {
        const int gi = i * 256 + t;
        const int cl = gi >> 3, g = gi & 7;
        const int c  = c0 + cl;
        float4 v = make_float4(0.f, 0.f, 0.f, 0.f);
        if (c < C_IN)
            v = *(const float4*)(y + ((size_t)(b * C_IN + c)) * HW + hw0 + g * 4);
        const int gp = g ^ ((cl >> 3) & 7);                // bank swizzle
        *(float4*)(tile + cl * 36 + gp * 4) = v;
    }
    __syncthreads();

    // write phase: each thread emits 8 bf16 codes (16 B) for one hw row
    #pragma unroll
    for (int it = 0; it < 2; ++it) {
        const int hw_r = (t >> 4) + it * 16;
        const int c8   = t & 15;
        const int c_out = c0 + c8 * 8;
        if (c_out < KPAD) {
            us8 pack;
            #pragma unroll
            for (int j = 0; j < 8; ++j) {
                const int cl = c8 * 8 + j;
                const int gp = (hw_r >> 2) ^ (c8 & 7);
                const float v = tile[cl * 36 + gp * 4 + (hw_r & 3)];
                const float k = fminf(fmaxf(floorf(v * inv_s), -128.f), 127.f);
                pack[j] = (unsigned short)(__float_as_uint(k) >> 16);
            }
            *(us8*)(yq + ((size_t)b * HW + hw0 + hw_r) * KPAD + c_out) = pack;
        }
    }
}

// GEMM: out[b][o][hw] = s_w*s_y * sum_c Wq[o][c] * Yq[b][hw][c]
// m97 structure + XOR granule swizzle (pre-swizzled global source, rule 21)
__global__ __launch_bounds__(256) void gemm_kernel(const unsigned short* __restrict__ Wq,
                                                   const unsigned short* __restrict__ Yq,
                                                   float* __restrict__ out,
                                                   const unsigned* __restrict__ slots) {
    __shared__ __align__(16) unsigned short As[128 * 32];
    __shared__ __align__(16) unsigned short Bs[128 * 32];
    const int t = threadIdx.x;
    const int w = t >> 6, l = t & 63;
    const int r = l & 15, q = l >> 4;
    const int wr = w >> 1, wc = w & 1;
    const int m0 = blockIdx.y * 128;
    const int n0 = blockIdx.x * 128;
    const int b  = blockIdx.z;

    const unsigned short* Ag = Wq + (size_t)m0 * KPAD;
    const unsigned short* Bg = Yq + ((size_t)b * HW + n0) * KPAD;

    const int srow = t >> 2;                       // staging row (0..63)
    // source granule pre-swizzle: slot s=(t&3) holds granule s ^ ((row>>1)&3)
    const int sko  = ((t & 3) ^ ((t >> 3) & 3)) * 8;
    const int swr  = (r >> 1) & 3;                 // read-side swizzle

    f32x4 acc[4][4];
    #pragma unroll
    for (int i = 0; i < 4; ++i)
        #pragma unroll
        for (int j = 0; j < 4; ++j) acc[i][j] = (f32x4){0.f, 0.f, 0.f, 0.f};

    for (int k0 = 0; k0 < KPAD; k0 += 32) {
        __builtin_amdgcn_global_load_lds(
            (const __attribute__((address_space(1))) void*)(Ag + (size_t)srow * KPAD + k0 + sko),
            (__attribute__((address_space(3))) void*)(As + w * 512), 16, 0, 0);
        __builtin_amdgcn_global_load_lds(
            (const __attribute__((address_space(1))) void*)(Ag + (size_t)(64 + srow) * KPAD + k0 + sko),
            (__attribute__((address_space(3))) void*)(As + 2048 + w * 512), 16, 0, 0);
        __builtin_amdgcn_global_load_lds(
            (const __attribute__((address_space(1))) void*)(Bg + (size_t)srow * KPAD + k0 + sko),
            (__attribute__((address_space(3))) void*)(Bs + w * 512), 16, 0, 0);
        __builtin_amdgcn_global_load_lds(
            (const __attribute__((address_space(1))) void*)(Bg + (size_t)(64 + srow) * KPAD + k0 + sko),
            (__attribute__((address_space(3))) void*)(Bs + 2048 + w * 512), 16, 0, 0);
        __syncthreads();

        bf16x8 af[4], bfr[4];
        #pragma unroll
        for (int fm = 0; fm < 4; ++fm)
            af[fm] = *(const bf16x8*)(As + (wr * 64 + fm * 16 + r) * 32 + ((q ^ swr)) * 8);
        #pragma unroll
        for (int fn = 0; fn < 4; ++fn)
            bfr[fn] = *(const bf16x8*)(Bs + (wc * 64 + fn * 16 + r) * 32 + ((q ^ swr)) * 8);
        #pragma unroll
        for (int fm = 0; fm < 4; ++fm)
            #pragma unroll
            for (int fn = 0; fn < 4; ++fn)
                acc[fm][fn] = __builtin_amdgcn_mfma_f32_16x16x32_bf16(
                    af[fm], bfr[fn], acc[fm][fn], 0, 0, 0);
        __syncthreads();
    }

    const float stot = p2scale(slots[1], 127.f) * p2scale(slots[2], 127.f);
    #pragma unroll
    for (int fm = 0; fm < 4; ++fm) {
        int o = m0 + wr * 64 + fm * 16 + q * 4;
        #pragma unroll
        for (int fn = 0; fn < 4; ++fn) {
            int hw = n0 + wc * 64 + fn * 16 + r;
            float* op = out + ((size_t)b * C_IN + o) * HW + hw;
            #pragma unroll
            for (int reg = 0; reg < 4; ++reg) {
                if (o + reg < C_IN) op[(size_t)reg * HW] = acc[fm][fn][reg] * stot;
            }
        }
    }
}

extern "C" void kernel_launch(void* const* d_in, const int* in_sizes, int n_in,
                              void* d_out, int out_size, void* d_ws, size_t ws_size,
                              hipStream_t stream) {
    const float* x     = (const float*)d_in[0];
    const float* w_dw  = (const float*)d_in[1];
    const float* w_pw  = (const float*)d_in[2];
    const float* gamma = (const float*)d_in[3];
    const float* beta  = (const float*)d_in[4];
    const float* rmean = (const float*)d_in[5];
    const float* rvar  = (const float*)d_in[6];
    float* out = (float*)d_out;

    char* ws = (char*)d_ws;
    unsigned*       slots = (unsigned*)ws;                         // 3 x u32
    float*          wq_dw = (float*)(ws + 256);                    // 6552 f32
    unsigned short* Wq    = (unsigned short*)(ws + 26624);         // [768][736] bf16
    float*          y     = (float*)(ws + 1157120);                // [16][728][4096] f32
    unsigned short* Yq    = (unsigned short*)(ws + 191997952);     // [16][4096][736] bf16
    // partial[] aliases the Yq region: consumed by reduce_partial BEFORE
    // transpose_quant_y writes Yq (stream-ordered, safe)
    float*          partial = (float*)(ws + 191997952);            // 11648 f32

    init_slots<<<dim3(1), dim3(64), 0, stream>>>(slots);
    maxabs_kernel<<<dim3(4), dim3(256), 0, stream>>>(w_dw, C_IN * 9, slots + 0);
    maxabs_kernel<<<dim3(64), dim3(256), 0, stream>>>(w_pw, C_IN * C_IN, slots + 1);
    quant_dw<<<dim3((C_IN * 9 + 255) / 256), dim3(256), 0, stream>>>(w_dw, wq_dw, slots);
    dwconv_bn<<<dim3(C_IN, NB), dim3(256), 0, stream>>>(
        x, wq_dw, gamma, beta, rmean, rvar, y, partial);
    reduce_partial<<<dim3(1), dim3(256), 0, stream>>>(partial, NB * C_IN, slots + 2);
    quant_wpw<<<dim3((MPAD * KPAD + 255) / 256), dim3(256), 0, stream>>>(w_pw, Wq, slots);
    transpose_quant_y<<<dim3(HW / 32, KPAD / 128 + 1, NB), dim3(256), 0, stream>>>(y, Yq, slots);
    gemm_kernel<<<dim3(HW / 128, MPAD / 128, NB), dim3(256), 0, stream>>>(Wq, Yq, out, slots);
}